// Round 8
// baseline (376.216 us; speedup 1.0000x reference)
//
#include <hip/hip_runtime.h>

// ---- problem constants ----
#define T_TOK   2048
#define HID     2048
#define NHEADS  32
#define NKV     4
#define HD      128
#define QSZ     4096          // 32*128
#define KVSZ    512           // 4*128
#define QKVW    5120          // QSZ + 2*KVSZ

typedef unsigned short u16;
typedef __bf16 bf16x8 __attribute__((ext_vector_type(8)));
typedef float  f32x4  __attribute__((ext_vector_type(4)));

__device__ __forceinline__ u16 f2bf(float f) {
  unsigned int u = __float_as_uint(f);
  u += 0x7fffu + ((u >> 16) & 1u);   // RNE
  return (u16)(u >> 16);
}

// native cast path: compiler emits v_cvt_pk_bf16_f32 (RNE, same result)
__device__ __forceinline__ u16 f2bf_n(float f) {
  __bf16 h = (__bf16)f;
  return __builtin_bit_cast(u16, h);
}

// async 16B global -> LDS (wave-uniform base + lane*16 semantics)
__device__ __forceinline__ void gl2lds16(const void* g, void* l) {
  __builtin_amdgcn_global_load_lds(
      (const __attribute__((address_space(1))) unsigned int*)g,
      (__attribute__((address_space(3))) unsigned int*)l, 16, 0, 0);
}

// 16-lane-group reductions via DPP row_ror (VALU latency vs __shfl_xor's
// LDS-pipe ds_swizzle). DPP rows are exactly our 16-lane groups.
template<int N>
__device__ __forceinline__ float rotmax(float x) {
  int t = __builtin_amdgcn_mov_dpp(__float_as_int(x), 0x120 | N, 0xf, 0xf, true);
  return fmaxf(x, __int_as_float(t));
}
template<int N>
__device__ __forceinline__ float rotadd(float x) {
  int t = __builtin_amdgcn_mov_dpp(__float_as_int(x), 0x120 | N, 0xf, 0xf, true);
  return x + __int_as_float(t);
}

// ---------------- fused fp32 -> bf16 convert (3 arrays, one launch) ---------
__global__ void cvt3_f32_bf16(const float* __restrict__ in0, u16* __restrict__ o0, int n0,
                              const float* __restrict__ in1, u16* __restrict__ o1, int n1,
                              const float* __restrict__ in2, u16* __restrict__ o2, int n2) {
  int i = blockIdx.x * blockDim.x + threadIdx.x;
  const float* in; u16* out;
  if (i < n0)            { in = in0; out = o0; }
  else if (i < n0 + n1)  { in = in1; out = o1; i -= n0; }
  else if (i < n0+n1+n2) { in = in2; out = o2; i -= n0 + n1; }
  else return;
  float4 v = ((const float4*)in)[i];
  ushort4 o;
  o.x = f2bf(v.x); o.y = f2bf(v.y); o.z = f2bf(v.z); o.w = f2bf(v.w);
  ((ushort4*)out)[i] = o;
}

// ---------------- NT GEMM: C[m][n] = sum_k A[m][k]*B[n][k] ----------------
// r5 configuration (349 us verified): BM=128 gemm1, BM=64 gemm2.
// Double-buffered LDS + one barrier per K-step; DMA of tile t+1 issued right
// after the barrier flies over tile t's ds_read+MFMA. launch_bounds(256,4).
// XCD-aware bijective block swizzle (T1; nwg % 8 == 0: 640, 512).
template<int BM>
__launch_bounds__(256, 4)
__global__ void gemm_nt(const u16* __restrict__ A, const u16* __restrict__ B,
                        float* __restrict__ C, int M, int N, int K) {
  constexpr int MI = BM / 32;          // m-tiles per wave
  __shared__ __align__(16) u16 As[2][BM * 32];
  __shared__ __align__(16) u16 Bs[2][128 * 32];
  const int tid  = threadIdx.x;
  const int wave = tid >> 6, lane = tid & 63;
  const int l15  = lane & 15, quad = lane >> 4;
  const int wr   = wave >> 1, wc = wave & 1;

  const int nwg = gridDim.x * gridDim.y;
  int lid = blockIdx.y * gridDim.x + blockIdx.x;
  lid = (lid & 7) * (nwg >> 3) + (lid >> 3);
  const int bx = lid % gridDim.x;
  const int by = lid / gridDim.x;

  const u16* Ab = A + (size_t)by * BM * K;
  const u16* Bb = B + (size_t)bx * 128 * K;

  f32x4 acc[MI][4];
#pragma unroll
  for (int i = 0; i < MI; i++)
#pragma unroll
    for (int j = 0; j < 4; j++) acc[i][j] = (f32x4){0.f, 0.f, 0.f, 0.f};

  constexpr int ACH = BM * 32 / 8;     // 16B chunks in A tile (multiple of 256)
  auto stage = [&](int t, int buf) {
    const int k0 = t * 32;
#pragma unroll
    for (int s = 0; s < (ACH + 512) / 256; s++) {
      int c = tid + s * 256;
      if (c < ACH) {
        int row = c >> 2, co = (c & 3) * 8;
        gl2lds16(Ab + (size_t)row * K + k0 + co, &As[buf][c * 8]);
      } else {
        int c2 = c - ACH;
        int row = c2 >> 2, co = (c2 & 3) * 8;
        gl2lds16(Bb + (size_t)row * K + k0 + co, &Bs[buf][c2 * 8]);
      }
    }
  };

  const int nst = K / 32;
  stage(0, 0);                         // prologue DMA, tile 0 -> buf 0

  for (int t = 0; t < nst; t++) {
    const int cur = t & 1;
    __syncthreads();                   // drains tile t's DMA; fences buf^1
    if (t + 1 < nst) stage(t + 1, cur ^ 1);

    bf16x8 af[MI], bf[4];
#pragma unroll
    for (int i = 0; i < MI; i++) af[i] = *(const bf16x8*)&As[cur][(wr * (BM / 2) + i * 16 + l15) * 32 + quad * 8];
#pragma unroll
    for (int j = 0; j < 4; j++) bf[j] = *(const bf16x8*)&Bs[cur][(wc * 64 + j * 16 + l15) * 32 + quad * 8];
#pragma unroll
    for (int i = 0; i < MI; i++)
#pragma unroll
      for (int j = 0; j < 4; j++)
        acc[i][j] = __builtin_amdgcn_mfma_f32_16x16x32_bf16(af[i], bf[j], acc[i][j], 0, 0, 0);
  }

  float* Cb = C + (size_t)by * BM * N + (size_t)bx * 128;
#pragma unroll
  for (int i = 0; i < MI; i++) {
    int rbase = wr * (BM / 2) + i * 16 + quad * 4;
#pragma unroll
    for (int j = 0; j < 4; j++) {
      int col = wc * 64 + j * 16 + l15;
#pragma unroll
      for (int r = 0; r < 4; r++) Cb[(size_t)(rbase + r) * N + col] = acc[i][j][r];
    }
  }
}

// ---------------- RMSNorm + RoPE + cast (one block per token) ----------------
// q additionally folds log2(e) so attention scores arrive in the exp2 domain.
__global__ void norm_rope(const float* __restrict__ qkv, const int* __restrict__ pos,
                          const float* __restrict__ qw, const float* __restrict__ kw,
                          u16* __restrict__ qB, u16* __restrict__ kB, u16* __restrict__ vB) {
  const int t = blockIdx.x;
  const int wave = threadIdx.x >> 6, l = threadIdx.x & 63;
  const float* row = qkv + (size_t)t * QKVW;

  constexpr float QSC = 0.08838834764831845f * 1.4426950408889634f; // 1/sqrt(HD) * log2(e)

  const float p = (float)pos[t];
  const float fr = p * exp2f(-(float)l * 0.20762050593046014f);
  float sn, cs;
  sincosf(fr, &sn, &cs);

  for (int slot = wave; slot < 40; slot += 4) {
    if (slot < 36) {
      const int   base = (slot < 32) ? slot * 128 : 4096 + (slot - 32) * 128;
      const float* w   = (slot < 32) ? qw : kw;
      float x1 = row[base + l], x2 = row[base + 64 + l];
      float ss = x1 * x1 + x2 * x2;
#pragma unroll
      for (int off = 32; off; off >>= 1) ss += __shfl_xor(ss, off);
      float rs = rsqrtf(ss * (1.f / 128.f) + 1e-6f);
      float n1 = x1 * rs * w[l], n2 = x2 * rs * w[64 + l];
      float o1 = n1 * cs - n2 * sn;
      float o2 = n2 * cs + n1 * sn;
      if (slot < 32) {
        o1 *= QSC;
        o2 *= QSC;
        qB[(size_t)t * QSZ + slot * 128 + l]      = f2bf(o1);
        qB[(size_t)t * QSZ + slot * 128 + 64 + l] = f2bf(o2);
      } else {
        kB[(size_t)t * KVSZ + (slot - 32) * 128 + l]      = f2bf(o1);
        kB[(size_t)t * KVSZ + (slot - 32) * 128 + 64 + l] = f2bf(o2);
      }
    } else {
      int vh = slot - 36;
      float x1 = row[4608 + vh * 128 + l];
      float x2 = row[4608 + vh * 128 + 64 + l];
      vB[(size_t)t * KVSZ + vh * 128 + l]      = f2bf(x1);
      vB[(size_t)t * KVSZ + vh * 128 + 64 + l] = f2bf(x2);
    }
  }
}

// ---------------- V transpose: vB (2048 x 512 u16) -> vT (512 x 2048 u16) ---
// LDS-tiled 64x64 transpose, 256 blocks, stride-65 LDS (~2-way, free).
__global__ void transpose_v(const u16* __restrict__ vB, u16* __restrict__ vT) {
  __shared__ u16 Ld[64 * 65];
  const int tb = blockIdx.x;                // token tile (64 wide)
  const int db = blockIdx.y;                // d tile (64 wide, over KVSZ=512)
  const int tid = threadIdx.x;
  const int r  = tid >> 3;                  // 0..31 (+s*32)
  const int c8 = (tid & 7) * 8;             // 0..56
#pragma unroll
  for (int s = 0; s < 2; s++) {
    int tr = r + s * 32;                    // token row in tile
    uint4 v = *(const uint4*)&vB[(size_t)(tb * 64 + tr) * KVSZ + db * 64 + c8];
    const u16* pv = (const u16*)&v;
#pragma unroll
    for (int j = 0; j < 8; j++) Ld[tr * 65 + c8 + j] = pv[j];
  }
  __syncthreads();
#pragma unroll
  for (int s = 0; s < 2; s++) {
    int dr = r + s * 32;                    // d row in tile
    uint4 v; u16* pv = (u16*)&v;
#pragma unroll
    for (int j = 0; j < 8; j++) pv[j] = Ld[(c8 + j) * 65 + dr];
    *(uint4*)&vT[(size_t)(db * 64 + dr) * T_TOK + tb * 64 + c8] = v;
  }
}

// ---------------- flash attention (causal, GQA 8:1) -------------------------
// r8: KVBLK 64 -> 128. r7 proved 512-thread blocks run 1 WG/CU regardless of
// LDS (occupancy pinned ~26% even at 64 KB) AND that each barrier costs
// ~770 cy. So: stop chasing co-residency, spend the idle 80 KB of LDS on
// 128-key tiles instead — barriers per block-pair 34 -> 17, 2x MFMA/DMA per
// barrier, 8 independent QK chains (vs 4) for better ILP at 2 waves/SIMD.
// LDS = K 2x32 + V 2x32 + P 32 = 160 KB exactly (AITER fmha runs 160KB/WG
// on this chip, m243). P stays wave-private (each wave writes/reads only its
// own 16-row strip) -> still ONE barrier per tile, no r7 mid-barrier.
// launch_bounds(512,2): 1 block/CU anyway -> 256-VGPR cap, no spill risk.
// All r5 machinery retained: DMA w/ pre-swizzled source (rule #21), DPP
// reduce, exp2-domain, defer-max THR=8, deferred l-sum, native casts,
// x-reversal pairing (pair tile total 17, uniform per CU even serially).
__launch_bounds__(512, 2)
__global__ void attn_fa(const u16* __restrict__ qB, const u16* __restrict__ kB,
                        const u16* __restrict__ vT, u16* __restrict__ oB) {
  const int qb  = (blockIdx.y < 16) ? (15 - (int)blockIdx.x) : (int)blockIdx.x;
  const int h   = blockIdx.y;
  const int kvh = h >> 3;
  __shared__ __align__(16) u16 Kb[2][128 * 16 * 8];  // [key][d], swizzled, 32 KB each
  __shared__ __align__(16) u16 Vb[2][128 * 16 * 8];  // [d][key], swizzled, 32 KB each
  __shared__ __align__(16) u16 Pb[128 * 16 * 8];     // [row][key], swizzled, 32 KB

  const int tid  = threadIdx.x;
  const int wave = tid >> 6, lane = tid & 63;
  const int l15  = lane & 15, quad = lane >> 4;

  // DMA one 128-key tile (K: [128key][128d] 32KB, V^T: [128d][128key] 32KB).
  // Linear LDS chunk c receives global chunk (c&mask)^(row-mask): the same
  // XOR involution the reads use, so read-side swizzles are unchanged.
  auto stage = [&](int kt, int buf) {
#pragma unroll
    for (int s = 0; s < 4; s++) {
      int c = tid + s * 512;                 // 16B chunk id, 0..2047
      int r = c >> 4;                        // key row 0..127
      gl2lds16(kB + (size_t)(kt * 128 + r) * KVSZ + kvh * 128 + ((c & 15) ^ (r & 15)) * 8,
               &Kb[buf][c * 8]);
    }
#pragma unroll
    for (int s = 0; s < 4; s++) {
      int c = tid + s * 512;                 // 16B chunk id, 0..2047
      int rv = c >> 4;                       // d row 0..127
      gl2lds16(vT + ((size_t)kvh * 128 + rv) * T_TOK + kt * 128 + ((c & 15) ^ (rv & 7)) * 8,
               &Vb[buf][c * 8]);
    }
  };

  bf16x8 qf[4];
#pragma unroll
  for (int ds = 0; ds < 4; ds++)
    qf[ds] = *(const bf16x8*)(qB + (size_t)(qb * 128 + wave * 16 + l15) * QSZ
                                 + h * 128 + ds * 32 + quad * 8);

  f32x4 o[8];
#pragma unroll
  for (int ni = 0; ni < 8; ni++) o[ni] = (f32x4){0.f, 0.f, 0.f, 0.f};
  float mrow[4], lrow[4];
#pragma unroll
  for (int r = 0; r < 4; r++) { mrow[r] = -3.0e38f; lrow[r] = 0.f; }

  const int nt = qb + 1;                       // 128-key tiles

  stage(0, 0);                                 // prologue DMA, tile 0 -> buf 0

  for (int kt = 0; kt < nt; kt++) {
    const int cur = kt & 1;
    // barrier: implicit vmcnt(0) drains tile kt's DMA for THIS wave, then
    // s_barrier makes every wave's DMA visible; also fences buf^1 readers.
    __syncthreads();
    if (kt + 1 < nt) stage(kt + 1, cur ^ 1);

    // S = Q K^T (16 rows x 128 keys per wave); 8 independent MFMA chains
    f32x4 sc[8];
#pragma unroll
    for (int ni = 0; ni < 8; ni++) sc[ni] = (f32x4){0.f, 0.f, 0.f, 0.f};
    __builtin_amdgcn_s_setprio(1);
#pragma unroll
    for (int ds = 0; ds < 4; ds++) {
#pragma unroll
      for (int ni = 0; ni < 8; ni++) {
        bf16x8 kf = *(const bf16x8*)&Kb[cur][((ni * 16 + l15) * 16 + ((ds * 4 + quad) ^ l15)) * 8];
        sc[ni] = __builtin_amdgcn_mfma_f32_16x16x32_bf16(qf[ds], kf, sc[ni], 0, 0, 0);
      }
    }
    __builtin_amdgcn_s_setprio(0);

    if (kt == qb) {  // only the last tile intersects the diagonal
#pragma unroll
      for (int ni = 0; ni < 8; ni++)
#pragma unroll
        for (int r = 0; r < 4; r++) {
          int key = kt * 128 + ni * 16 + l15;
          int rw  = qb * 128 + wave * 16 + quad * 4 + r;
          if (key > rw) sc[ni][r] = -1.0e30f;
        }
    }

    // online softmax in exp2 domain, defer-max THR=8, per-lane l partials
#pragma unroll
    for (int r = 0; r < 4; r++) {
      float mx = fmaxf(fmaxf(fmaxf(sc[0][r], sc[1][r]), fmaxf(sc[2][r], sc[3][r])),
                       fmaxf(fmaxf(sc[4][r], sc[5][r]), fmaxf(sc[6][r], sc[7][r])));
      mx = rotmax<1>(mx); mx = rotmax<2>(mx); mx = rotmax<4>(mx); mx = rotmax<8>(mx);
      if (!__all(mx <= mrow[r] + 8.f)) {
        float mn = fmaxf(mrow[r], mx);
        float al = exp2f(mrow[r] - mn);      // group-uniform
        mrow[r]  = mn;
        lrow[r] *= al;                       // per-lane partial stays consistent
#pragma unroll
        for (int ni = 0; ni < 8; ni++) o[ni][r] *= al;
      }
      float rs = 0.f;
#pragma unroll
      for (int ni = 0; ni < 8; ni++) {
        float pv = exp2f(sc[ni][r] - mrow[r]);
        sc[ni][r] = pv;
        rs += pv;
      }
      lrow[r] += rs;                         // no cross-lane reduce here
    }

    // P (own 16-row strip) -> swizzled Pb; strip-private => no barrier
#pragma unroll
    for (int ni = 0; ni < 8; ni++)
#pragma unroll
      for (int r = 0; r < 4; r++) {
        int row = wave * 16 + quad * 4 + r;
        Pb[(row * 16 + ((ni * 2 + (l15 >> 3)) ^ (row & 7))) * 8 + (l15 & 7)] =
            f2bf_n(sc[ni][r]);
      }

    // O += P V  (A = own P strip, B = V^T tile), K-span 4 x 32 keys
    __builtin_amdgcn_s_setprio(1);
#pragma unroll
    for (int ks = 0; ks < 4; ks++) {
      bf16x8 pf = *(const bf16x8*)&Pb[((wave * 16 + l15) * 16 + ((ks * 4 + quad) ^ (l15 & 7))) * 8];
#pragma unroll
      for (int ni = 0; ni < 8; ni++) {
        bf16x8 vf = *(const bf16x8*)&Vb[cur][((ni * 16 + l15) * 16 + ((ks * 4 + quad) ^ (l15 & 7))) * 8];
        o[ni] = __builtin_amdgcn_mfma_f32_16x16x32_bf16(pf, vf, o[ni], 0, 0, 0);
      }
    }
    __builtin_amdgcn_s_setprio(0);
  }

  // epilogue: reduce the deferred per-lane l partials ONCE, then O * (1/l)
#pragma unroll
  for (int r = 0; r < 4; r++) {
    float s = lrow[r];
    s = rotadd<1>(s); s = rotadd<2>(s); s = rotadd<4>(s); s = rotadd<8>(s);
    float rinv = 1.0f / s;
    int t = qb * 128 + wave * 16 + quad * 4 + r;
#pragma unroll
    for (int ni = 0; ni < 8; ni++)
      oB[(size_t)t * QSZ + h * 128 + ni * 16 + l15] = f2bf_n(o[ni][r] * rinv);
  }
}

// ---------------- launch ----------------
extern "C" void kernel_launch(void* const* d_in, const int* in_sizes, int n_in,
                              void* d_out, int out_size, void* d_ws, size_t ws_size,
                              hipStream_t stream) {
  const int*   positions = (const int*)d_in[0];
  const float* hidden    = (const float*)d_in[1];
  const float* w_qkv     = (const float*)d_in[2];
  const float* w_o       = (const float*)d_in[3];
  const float* qw        = (const float*)d_in[4];
  const float* kw        = (const float*)d_in[5];
  float* out = (float*)d_out;
  char*  ws  = (char*)d_ws;

  u16* hiddenB = (u16*)ws;
  u16* wqkvB   = hiddenB + (size_t)HID * HID;
  u16* woB     = wqkvB + (size_t)QKVW * HID;
  size_t off1  = ((size_t)HID * HID + (size_t)QKVW * HID + (size_t)HID * QSZ) * 2;
  float* qkvF  = (float*)(ws + off1);
  u16*   attnB = (u16*)(ws + off1);                          // alias (dead qkvF)
  size_t off2  = off1 + (size_t)T_TOK * QKVW * 4;
  u16* qBuf = (u16*)(ws + off2);
  size_t off3  = off2 + (size_t)T_TOK * QSZ * 2;
  u16* kBuf = (u16*)(ws + off3);
  size_t off4  = off3 + (size_t)T_TOK * KVSZ * 2;
  u16* vTb  = (u16*)(ws + off4);
  size_t off5  = off4 + (size_t)T_TOK * KVSZ * 2;
  u16* vBuf = (u16*)(ws + off5);

  const int n0 = HID * HID / 4, n1 = QKVW * HID / 4, n2 = HID * QSZ / 4;
  cvt3_f32_bf16<<<(n0 + n1 + n2 + 255) / 256, 256, 0, stream>>>(
      hidden, hiddenB, n0, w_qkv, wqkvB, n1, w_o, woB, n2);

  gemm_nt<128><<<dim3(QKVW / 128, T_TOK / 128), 256, 0, stream>>>(hiddenB, wqkvB, qkvF, T_TOK, QKVW, HID);

  norm_rope<<<T_TOK, 256, 0, stream>>>(qkvF, positions, qw, kw, qBuf, kBuf, vBuf);

  transpose_v<<<dim3(T_TOK / 64, KVSZ / 64), 256, 0, stream>>>(vBuf, vTb);

  attn_fa<<<dim3(T_TOK / 128, NHEADS), 512, 0, stream>>>(qBuf, kBuf, vTb, attnB);

  gemm_nt<64><<<dim3(HID / 128, T_TOK / 64), 256, 0, stream>>>(attnB, woB, out, T_TOK, HID, QSZ);
}

// Round 9
// 344.191 us; speedup vs baseline: 1.0930x; 1.0930x over previous
//
#include <hip/hip_runtime.h>

// ---- problem constants ----
#define T_TOK   2048
#define HID     2048
#define NHEADS  32
#define NKV     4
#define HD      128
#define QSZ     4096          // 32*128
#define KVSZ    512           // 4*128
#define QKVW    5120          // QSZ + 2*KVSZ

typedef unsigned short u16;
typedef __bf16 bf16x8 __attribute__((ext_vector_type(8)));
typedef float  f32x4  __attribute__((ext_vector_type(4)));

__device__ __forceinline__ u16 f2bf(float f) {
  unsigned int u = __float_as_uint(f);
  u += 0x7fffu + ((u >> 16) & 1u);   // RNE
  return (u16)(u >> 16);
}

// native cast path: compiler emits v_cvt_pk_bf16_f32 (RNE, same result)
__device__ __forceinline__ u16 f2bf_n(float f) {
  __bf16 h = (__bf16)f;
  return __builtin_bit_cast(u16, h);
}

// bf16 -> f32 (exact)
__device__ __forceinline__ float bf2f(u16 u) {
  return __uint_as_float((unsigned int)u << 16);
}

// async 16B global -> LDS (wave-uniform base + lane*16 semantics)
__device__ __forceinline__ void gl2lds16(const void* g, void* l) {
  __builtin_amdgcn_global_load_lds(
      (const __attribute__((address_space(1))) unsigned int*)g,
      (__attribute__((address_space(3))) unsigned int*)l, 16, 0, 0);
}

// 16-lane-group reductions via DPP row_ror (VALU latency vs __shfl_xor's
// LDS-pipe ds_swizzle). DPP rows are exactly our 16-lane groups.
template<int N>
__device__ __forceinline__ float rotmax(float x) {
  int t = __builtin_amdgcn_mov_dpp(__float_as_int(x), 0x120 | N, 0xf, 0xf, true);
  return fmaxf(x, __int_as_float(t));
}
template<int N>
__device__ __forceinline__ float rotadd(float x) {
  int t = __builtin_amdgcn_mov_dpp(__float_as_int(x), 0x120 | N, 0xf, 0xf, true);
  return x + __int_as_float(t);
}

// ---------------- fused fp32 -> bf16 convert (3 arrays, one launch) ---------
__global__ void cvt3_f32_bf16(const float* __restrict__ in0, u16* __restrict__ o0, int n0,
                              const float* __restrict__ in1, u16* __restrict__ o1, int n1,
                              const float* __restrict__ in2, u16* __restrict__ o2, int n2) {
  int i = blockIdx.x * blockDim.x + threadIdx.x;
  const float* in; u16* out;
  if (i < n0)            { in = in0; out = o0; }
  else if (i < n0 + n1)  { in = in1; out = o1; i -= n0; }
  else if (i < n0+n1+n2) { in = in2; out = o2; i -= n0 + n1; }
  else return;
  float4 v = ((const float4*)in)[i];
  ushort4 o;
  o.x = f2bf(v.x); o.y = f2bf(v.y); o.z = f2bf(v.z); o.w = f2bf(v.w);
  ((ushort4*)out)[i] = o;
}

// ---------------- NT GEMM: C[m][n] = sum_k A[m][k]*B[n][k] ----------------
// r5 configuration (349 us verified): BM=128 gemm1, BM=64 gemm2.
// Double-buffered LDS + one barrier per K-step; DMA of tile t+1 issued right
// after the barrier flies over tile t's ds_read+MFMA. launch_bounds(256,4).
// XCD-aware bijective block swizzle (T1; nwg % 8 == 0: 640, 512).
// r9: OUT16 template — gemm1 writes bf16 qkv directly (saves 21 MB write +
// 21 MB read in norm_rope); gemm2 still writes f32 (final output).
template<int BM, bool OUT16>
__launch_bounds__(256, 4)
__global__ void gemm_nt(const u16* __restrict__ A, const u16* __restrict__ B,
                        void* __restrict__ Cv, int M, int N, int K) {
  constexpr int MI = BM / 32;          // m-tiles per wave
  __shared__ __align__(16) u16 As[2][BM * 32];
  __shared__ __align__(16) u16 Bs[2][128 * 32];
  const int tid  = threadIdx.x;
  const int wave = tid >> 6, lane = tid & 63;
  const int l15  = lane & 15, quad = lane >> 4;
  const int wr   = wave >> 1, wc = wave & 1;

  const int nwg = gridDim.x * gridDim.y;
  int lid = blockIdx.y * gridDim.x + blockIdx.x;
  lid = (lid & 7) * (nwg >> 3) + (lid >> 3);
  const int bx = lid % gridDim.x;
  const int by = lid / gridDim.x;

  const u16* Ab = A + (size_t)by * BM * K;
  const u16* Bb = B + (size_t)bx * 128 * K;

  f32x4 acc[MI][4];
#pragma unroll
  for (int i = 0; i < MI; i++)
#pragma unroll
    for (int j = 0; j < 4; j++) acc[i][j] = (f32x4){0.f, 0.f, 0.f, 0.f};

  constexpr int ACH = BM * 32 / 8;     // 16B chunks in A tile (multiple of 256)
  auto stage = [&](int t, int buf) {
    const int k0 = t * 32;
#pragma unroll
    for (int s = 0; s < (ACH + 512) / 256; s++) {
      int c = tid + s * 256;
      if (c < ACH) {
        int row = c >> 2, co = (c & 3) * 8;
        gl2lds16(Ab + (size_t)row * K + k0 + co, &As[buf][c * 8]);
      } else {
        int c2 = c - ACH;
        int row = c2 >> 2, co = (c2 & 3) * 8;
        gl2lds16(Bb + (size_t)row * K + k0 + co, &Bs[buf][c2 * 8]);
      }
    }
  };

  const int nst = K / 32;
  stage(0, 0);                         // prologue DMA, tile 0 -> buf 0

  for (int t = 0; t < nst; t++) {
    const int cur = t & 1;
    __syncthreads();                   // drains tile t's DMA; fences buf^1
    if (t + 1 < nst) stage(t + 1, cur ^ 1);

    bf16x8 af[MI], bf[4];
#pragma unroll
    for (int i = 0; i < MI; i++) af[i] = *(const bf16x8*)&As[cur][(wr * (BM / 2) + i * 16 + l15) * 32 + quad * 8];
#pragma unroll
    for (int j = 0; j < 4; j++) bf[j] = *(const bf16x8*)&Bs[cur][(wc * 64 + j * 16 + l15) * 32 + quad * 8];
#pragma unroll
    for (int i = 0; i < MI; i++)
#pragma unroll
      for (int j = 0; j < 4; j++)
        acc[i][j] = __builtin_amdgcn_mfma_f32_16x16x32_bf16(af[i], bf[j], acc[i][j], 0, 0, 0);
  }

#pragma unroll
  for (int i = 0; i < MI; i++) {
    int rbase = wr * (BM / 2) + i * 16 + quad * 4;
#pragma unroll
    for (int j = 0; j < 4; j++) {
      int col = wc * 64 + j * 16 + l15;
#pragma unroll
      for (int r = 0; r < 4; r++) {
        size_t idx = (size_t)(by * BM + rbase + r) * N + bx * 128 + col;
        if constexpr (OUT16) ((u16*)Cv)[idx] = f2bf_n(acc[i][j][r]);
        else                 ((float*)Cv)[idx] = acc[i][j][r];
      }
    }
  }
}

// ---------------- RMSNorm + RoPE + cast (one block per token) ----------------
// r9: input is bf16 qkv (from gemm1's OUT16 epilogue); upconvert is exact.
// q folds 1/sqrt(HD) * log2(e) so scores arrive in the exp2 domain.
// Reduce: 4 DPP rotadd steps (16-lane rows) + 2 __shfl_xor (cross-row).
__global__ void norm_rope(const u16* __restrict__ qkv, const int* __restrict__ pos,
                          const float* __restrict__ qw, const float* __restrict__ kw,
                          u16* __restrict__ qB, u16* __restrict__ kB, u16* __restrict__ vB) {
  const int t = blockIdx.x;
  const int wave = threadIdx.x >> 6, l = threadIdx.x & 63;
  const u16* row = qkv + (size_t)t * QKVW;

  constexpr float QSC = 0.08838834764831845f * 1.4426950408889634f; // 1/sqrt(HD) * log2(e)

  const float p = (float)pos[t];
  const float fr = p * exp2f(-(float)l * 0.20762050593046014f);
  float sn, cs;
  sincosf(fr, &sn, &cs);

  for (int slot = wave; slot < 40; slot += 4) {
    if (slot < 36) {
      const int   base = (slot < 32) ? slot * 128 : 4096 + (slot - 32) * 128;
      const float* w   = (slot < 32) ? qw : kw;
      float x1 = bf2f(row[base + l]), x2 = bf2f(row[base + 64 + l]);
      float ss = x1 * x1 + x2 * x2;
      ss = rotadd<1>(ss); ss = rotadd<2>(ss); ss = rotadd<4>(ss); ss = rotadd<8>(ss);
      ss += __shfl_xor(ss, 16);
      ss += __shfl_xor(ss, 32);
      float rs = rsqrtf(ss * (1.f / 128.f) + 1e-6f);
      float n1 = x1 * rs * w[l], n2 = x2 * rs * w[64 + l];
      float o1 = n1 * cs - n2 * sn;
      float o2 = n2 * cs + n1 * sn;
      if (slot < 32) {
        o1 *= QSC;
        o2 *= QSC;
        qB[(size_t)t * QSZ + slot * 128 + l]      = f2bf(o1);
        qB[(size_t)t * QSZ + slot * 128 + 64 + l] = f2bf(o2);
      } else {
        kB[(size_t)t * KVSZ + (slot - 32) * 128 + l]      = f2bf(o1);
        kB[(size_t)t * KVSZ + (slot - 32) * 128 + 64 + l] = f2bf(o2);
      }
    } else {
      int vh = slot - 36;
      // v passes through: already bf16, bit-identical to old f2bf(f32) path
      vB[(size_t)t * KVSZ + vh * 128 + l]      = row[4608 + vh * 128 + l];
      vB[(size_t)t * KVSZ + vh * 128 + 64 + l] = row[4608 + vh * 128 + 64 + l];
    }
  }
}

// ---------------- V transpose: vB (2048 x 512 u16) -> vT (512 x 2048 u16) ---
// LDS-tiled 64x64 transpose, 256 blocks, stride-65 LDS (~2-way, free).
__global__ void transpose_v(const u16* __restrict__ vB, u16* __restrict__ vT) {
  __shared__ u16 Ld[64 * 65];
  const int tb = blockIdx.x;                // token tile (64 wide)
  const int db = blockIdx.y;                // d tile (64 wide, over KVSZ=512)
  const int tid = threadIdx.x;
  const int r  = tid >> 3;                  // 0..31 (+s*32)
  const int c8 = (tid & 7) * 8;             // 0..56
#pragma unroll
  for (int s = 0; s < 2; s++) {
    int tr = r + s * 32;                    // token row in tile
    uint4 v = *(const uint4*)&vB[(size_t)(tb * 64 + tr) * KVSZ + db * 64 + c8];
    const u16* pv = (const u16*)&v;
#pragma unroll
    for (int j = 0; j < 8; j++) Ld[tr * 65 + c8 + j] = pv[j];
  }
  __syncthreads();
#pragma unroll
  for (int s = 0; s < 2; s++) {
    int dr = r + s * 32;                    // d row in tile
    uint4 v; u16* pv = (u16*)&v;
#pragma unroll
    for (int j = 0; j < 8; j++) pv[j] = Ld[(c8 + j) * 65 + dr];
    *(uint4*)&vT[(size_t)(db * 64 + dr) * T_TOK + tb * 64 + c8] = v;
  }
}

// ---------------- flash attention (causal, GQA 8:1) -------------------------
// r9: EXACT r5 revert — the verified local optimum (88.3 us, 0 conflicts,
// VGPR 64). r6-r8 mapped the neighborhood: bigger KV tiles (r8: 16-chunk rows
// break the bank-XOR geometry, 5M conflicts), LDS-alias+mid-barrier (r7:
// +770cy/barrier, no co-residency), co-residency chasing (r7: 512-thr blocks
// pin at 1 WG/CU regardless of LDS) — all regress.
// Structure: 512 thr / 8 waves, 128-row q-strips, 64-key tiles, double-
// buffered K/V via global_load_lds with PRE-SWIZZLED source (rule #21), one
// barrier/tile, x-reversal pairing. DPP rotate-reduce softmax, exp2-domain,
// defer-max THR=8, deferred per-lane l-sum, native bf16 casts.
__launch_bounds__(512, 4)
__global__ void attn_fa(const u16* __restrict__ qB, const u16* __restrict__ kB,
                        const u16* __restrict__ vT, u16* __restrict__ oB) {
  const int qb  = (blockIdx.y < 16) ? (15 - (int)blockIdx.x) : (int)blockIdx.x;
  const int h   = blockIdx.y;
  const int kvh = h >> 3;
  __shared__ __align__(16) u16 Kb[2][64 * 16 * 8];   // [key][d], swizzled, 16 KB each
  __shared__ __align__(16) u16 Vb[2][128 * 8 * 8];   // [d][key], swizzled, 16 KB each
  __shared__ __align__(16) u16 Pb[128 * 8 * 8];      // [row][key], swizzled, 16 KB

  const int tid  = threadIdx.x;
  const int wave = tid >> 6, lane = tid & 63;
  const int l15  = lane & 15, quad = lane >> 4;

  auto stage = [&](int kt, int buf) {
#pragma unroll
    for (int s = 0; s < 2; s++) {
      int c = tid + s * 512;                 // 16B chunk id, 0..1023
      int r = c >> 4;                        // key row 0..63
      gl2lds16(kB + (size_t)(kt * 64 + r) * KVSZ + kvh * 128 + ((c & 15) ^ (r & 15)) * 8,
               &Kb[buf][c * 8]);
    }
#pragma unroll
    for (int s = 0; s < 2; s++) {
      int c = tid + s * 512;                 // 16B chunk id, 0..1023
      int rv = c >> 3;                       // d row 0..127
      gl2lds16(vT + ((size_t)kvh * 128 + rv) * T_TOK + kt * 64 + ((c & 7) ^ (rv & 7)) * 8,
               &Vb[buf][c * 8]);
    }
  };

  bf16x8 qf[4];
#pragma unroll
  for (int ds = 0; ds < 4; ds++)
    qf[ds] = *(const bf16x8*)(qB + (size_t)(qb * 128 + wave * 16 + l15) * QSZ
                                 + h * 128 + ds * 32 + quad * 8);

  f32x4 o[8];
#pragma unroll
  for (int ni = 0; ni < 8; ni++) o[ni] = (f32x4){0.f, 0.f, 0.f, 0.f};
  float mrow[4], lrow[4];
#pragma unroll
  for (int r = 0; r < 4; r++) { mrow[r] = -3.0e38f; lrow[r] = 0.f; }

  const int nt = 2 * qb + 2;                   // 64-key tiles

  stage(0, 0);                                 // prologue DMA, tile 0 -> buf 0

  for (int kt = 0; kt < nt; kt++) {
    const int cur = kt & 1;
    // barrier: implicit vmcnt(0) drains tile kt's DMA for THIS wave, then
    // s_barrier makes every wave's DMA visible; also fences buf^1 readers.
    __syncthreads();
    if (kt + 1 < nt) stage(kt + 1, cur ^ 1);

    // S = Q K^T (16 rows x 64 keys per wave)
    f32x4 sc[4];
#pragma unroll
    for (int ni = 0; ni < 4; ni++) sc[ni] = (f32x4){0.f, 0.f, 0.f, 0.f};
    __builtin_amdgcn_s_setprio(1);
#pragma unroll
    for (int ds = 0; ds < 4; ds++) {
#pragma unroll
      for (int ni = 0; ni < 4; ni++) {
        bf16x8 kf = *(const bf16x8*)&Kb[cur][((ni * 16 + l15) * 16 + ((ds * 4 + quad) ^ l15)) * 8];
        sc[ni] = __builtin_amdgcn_mfma_f32_16x16x32_bf16(qf[ds], kf, sc[ni], 0, 0, 0);
      }
    }
    __builtin_amdgcn_s_setprio(0);

    if (kt >= 2 * qb) {  // tiles intersecting the diagonal
#pragma unroll
      for (int ni = 0; ni < 4; ni++)
#pragma unroll
        for (int r = 0; r < 4; r++) {
          int key = kt * 64 + ni * 16 + l15;
          int rw  = qb * 128 + wave * 16 + quad * 4 + r;
          if (key > rw) sc[ni][r] = -1.0e30f;
        }
    }

    // online softmax in exp2 domain, defer-max THR=8, per-lane l partials
#pragma unroll
    for (int r = 0; r < 4; r++) {
      float mx = fmaxf(fmaxf(sc[0][r], sc[1][r]), fmaxf(sc[2][r], sc[3][r]));
      mx = rotmax<1>(mx); mx = rotmax<2>(mx); mx = rotmax<4>(mx); mx = rotmax<8>(mx);
      if (!__all(mx <= mrow[r] + 8.f)) {
        float mn = fmaxf(mrow[r], mx);
        float al = exp2f(mrow[r] - mn);      // group-uniform
        mrow[r]  = mn;
        lrow[r] *= al;                       // per-lane partial stays consistent
#pragma unroll
        for (int ni = 0; ni < 8; ni++) o[ni][r] *= al;
      }
      float rs = 0.f;
#pragma unroll
      for (int ni = 0; ni < 4; ni++) {
        float pv = exp2f(sc[ni][r] - mrow[r]);
        sc[ni][r] = pv;
        rs += pv;
      }
      lrow[r] += rs;                         // no cross-lane reduce here
    }

    // P (own 16-row strip) -> swizzled Pb; strip-private => no barrier
#pragma unroll
    for (int ni = 0; ni < 4; ni++)
#pragma unroll
      for (int r = 0; r < 4; r++) {
        int row = wave * 16 + quad * 4 + r;
        Pb[(row * 8 + ((ni * 2 + (l15 >> 3)) ^ (row & 7))) * 8 + (l15 & 7)] =
            f2bf_n(sc[ni][r]);
      }

    // O += P V  (A = own P strip, B = V^T tile)
    __builtin_amdgcn_s_setprio(1);
#pragma unroll
    for (int ks = 0; ks < 2; ks++) {
      bf16x8 pf = *(const bf16x8*)&Pb[((wave * 16 + l15) * 8 + ((ks * 4 + quad) ^ (l15 & 7))) * 8];
#pragma unroll
      for (int ni = 0; ni < 8; ni++) {
        bf16x8 vf = *(const bf16x8*)&Vb[cur][((ni * 16 + l15) * 8 + ((ks * 4 + quad) ^ (l15 & 7))) * 8];
        o[ni] = __builtin_amdgcn_mfma_f32_16x16x32_bf16(pf, vf, o[ni], 0, 0, 0);
      }
    }
    __builtin_amdgcn_s_setprio(0);
  }

  // epilogue: reduce the deferred per-lane l partials ONCE, then O * (1/l)
#pragma unroll
  for (int r = 0; r < 4; r++) {
    float s = lrow[r];
    s = rotadd<1>(s); s = rotadd<2>(s); s = rotadd<4>(s); s = rotadd<8>(s);
    float rinv = 1.0f / s;
    int t = qb * 128 + wave * 16 + quad * 4 + r;
#pragma unroll
    for (int ni = 0; ni < 8; ni++)
      oB[(size_t)t * QSZ + h * 128 + ni * 16 + l15] = f2bf_n(o[ni][r] * rinv);
  }
}

// ---------------- launch ----------------
extern "C" void kernel_launch(void* const* d_in, const int* in_sizes, int n_in,
                              void* d_out, int out_size, void* d_ws, size_t ws_size,
                              hipStream_t stream) {
  const int*   positions = (const int*)d_in[0];
  const float* hidden    = (const float*)d_in[1];
  const float* w_qkv     = (const float*)d_in[2];
  const float* w_o       = (const float*)d_in[3];
  const float* qw        = (const float*)d_in[4];
  const float* kw        = (const float*)d_in[5];
  float* out = (float*)d_out;
  char*  ws  = (char*)d_ws;

  u16* hiddenB = (u16*)ws;
  u16* wqkvB   = hiddenB + (size_t)HID * HID;
  u16* woB     = wqkvB + (size_t)QKVW * HID;
  size_t off1  = ((size_t)HID * HID + (size_t)QKVW * HID + (size_t)HID * QSZ) * 2;
  u16* qkvB    = (u16*)(ws + off1);                          // bf16 qkv (r9)
  u16* attnB   = (u16*)(ws + off1);                          // alias (dead qkvB)
  size_t off2  = off1 + (size_t)T_TOK * QKVW * 4;            // keep r5 layout
  u16* qBuf = (u16*)(ws + off2);
  size_t off3  = off2 + (size_t)T_TOK * QSZ * 2;
  u16* kBuf = (u16*)(ws + off3);
  size_t off4  = off3 + (size_t)T_TOK * KVSZ * 2;
  u16* vTb  = (u16*)(ws + off4);
  size_t off5  = off4 + (size_t)T_TOK * KVSZ * 2;
  u16* vBuf = (u16*)(ws + off5);

  const int n0 = HID * HID / 4, n1 = QKVW * HID / 4, n2 = HID * QSZ / 4;
  cvt3_f32_bf16<<<(n0 + n1 + n2 + 255) / 256, 256, 0, stream>>>(
      hidden, hiddenB, n0, w_qkv, wqkvB, n1, w_o, woB, n2);

  gemm_nt<128, true><<<dim3(QKVW / 128, T_TOK / 128), 256, 0, stream>>>(
      hiddenB, wqkvB, qkvB, T_TOK, QKVW, HID);

  norm_rope<<<T_TOK, 256, 0, stream>>>(qkvB, positions, qw, kw, qBuf, kBuf, vBuf);

  transpose_v<<<dim3(T_TOK / 64, KVSZ / 64), 256, 0, stream>>>(vBuf, vTb);

  attn_fa<<<dim3(T_TOK / 128, NHEADS), 512, 0, stream>>>(qBuf, kBuf, vTb, attnB);

  gemm_nt<64, false><<<dim3(HID / 128, T_TOK / 64), 256, 0, stream>>>(
      attnB, woB, out, T_TOK, HID, QSZ);
}